// Round 10
// baseline (790.457 us; speedup 1.0000x reference)
//
#include <hip/hip_runtime.h>
#include <hip/hip_bf16.h>

#define B 64
#define N 1024
#define E 8192
#define EP (E + N)      // 9216 edges incl self-loops
#define C 3
#define H 152
#define NC 10
#define FC_IN 611       // C + 4*H
#define KP 160          // padded H (5 * 32)
#define NT 10           // n-tiles of 16
#define KS 5            // k-steps of 32
#define NFRAG (NT * KS * 64)   // 3200 fragments of 8 bf16
#define CCH 32          // cols per aggregate chunk
#define NCHK 5          // chunks (5*32 = 160 >= 152)

typedef __attribute__((ext_vector_type(8))) short bf16x8;
typedef __attribute__((ext_vector_type(4))) float f32x4;

// ---------------- static scratch ----------------
__device__ __hip_bfloat16 g_hAhi[B * N][KP];       // layer outputs hi (bf16, padded)
__device__ __hip_bfloat16 g_hAlo[B * N][KP];       // layer outputs lo residual
__device__ float g_hB[B * N * H];                  // transformed features h = in @ W
__device__ float g_hs[B * N];
__device__ float g_hd[B * N];
__device__ float g_wgt[B * EP];                    // normalized edge weights
__device__ float g_pooled[B * FC_IN];
__device__ __hip_bfloat16 g_Wfhi[3][NFRAG * 8];    // W^T hi, fragment-ordered
__device__ __hip_bfloat16 g_Wflo[3][NFRAG * 8];    // W^T lo, fragment-ordered
__device__ int   g_cnt[B * N];
__device__ int   g_woff[B * N];
__device__ int   g_offs[B * (N + 1)];
__device__ int   g_ssrc[B * EP];

// ---------------- init ----------------
__global__ void k_zero() {
    int i = blockIdx.x * blockDim.x + threadIdx.x;
    if (i < B * N) g_cnt[i] = 0;
    if (i < B * FC_IN) g_pooled[i] = 0.f;
}

// pack W^T split into MFMA-fragment order:
// frag i (= (nt*KS+ks)*64 + ln): elem j = W[(ks*32+(ln>>4)*8+j)][nt*16+(ln&15)]
__global__ void k_packW(const float* __restrict__ W234) {
    int gid = blockIdx.x * 256 + threadIdx.x;
    if (gid >= 3 * NFRAG * 8) return;
    int l = gid / (NFRAG * 8);
    int rem = gid - l * (NFRAG * 8);
    int i = rem >> 3, j = rem & 7;
    int frag = i >> 6, ln = i & 63;
    int nt = frag / KS, ks = frag - nt * KS;
    int n = nt * 16 + (ln & 15);
    int kk = ks * 32 + (ln >> 4) * 8 + j;
    float v = (n < H && kk < H) ? W234[(l * H + kk) * H + n] : 0.f;
    __hip_bfloat16 hi = __float2bfloat16(v);
    float lo = v - __bfloat162float(hi);
    g_Wfhi[l][rem] = hi;
    g_Wflo[l][rem] = __float2bfloat16(lo);
}

// ---------------- CSR build ----------------
__global__ void k_count(const int* __restrict__ ei) {
    int gid = blockIdx.x * 256 + threadIdx.x;
    if (gid >= B * E) return;
    int b = gid >> 13;
    int e = gid & (E - 1);
    int dst = ei[b * 2 * E + E + e];
    atomicAdd(&g_cnt[b * N + dst], 1);
}

__global__ __launch_bounds__(1024) void k_scan() {
    int b = blockIdx.x, t = threadIdx.x;
    __shared__ int s[N];
    int v = g_cnt[b * N + t] + 1;          // +1 self loop
    s[t] = v;
    __syncthreads();
    for (int d = 1; d < N; d <<= 1) {
        int add = (t >= d) ? s[t - d] : 0;
        __syncthreads();
        s[t] += add;
        __syncthreads();
    }
    int incl = s[t], excl = incl - v;
    g_offs[b * (N + 1) + t + 1] = incl;
    if (t == 0) g_offs[b * (N + 1)] = 0;
    g_ssrc[b * EP + excl] = t;             // self loop first in bucket
    g_woff[b * N + t] = excl + 1;
}

__global__ void k_scatter(const int* __restrict__ ei) {
    int gid = blockIdx.x * 256 + threadIdx.x;
    if (gid >= B * E) return;
    int b = gid >> 13;
    int e = gid & (E - 1);
    int src = ei[b * 2 * E + e];
    int dst = ei[b * 2 * E + E + e];
    int pos = atomicAdd(&g_woff[b * N + dst], 1);
    g_ssrc[b * EP + pos] = src;
}

// ---------------- x pooling ----------------
__global__ void k_pool_x(const float* __restrict__ x) {
    int b = blockIdx.x, t = threadIdx.x;
    float a0 = 0, a1 = 0, a2 = 0;
    for (int n = t; n < N; n += 256) {
        const float* p = x + (b * N + n) * C;
        a0 += p[0]; a1 += p[1]; a2 += p[2];
    }
    __shared__ float s[3][256];
    s[0][t] = a0; s[1][t] = a1; s[2][t] = a2;
    __syncthreads();
    for (int d = 128; d > 0; d >>= 1) {
        if (t < d) {
            s[0][t] += s[0][t + d];
            s[1][t] += s[1][t + d];
            s[2][t] += s[2][t + d];
        }
        __syncthreads();
    }
    if (t < 3) g_pooled[b * FC_IN + t] = s[t][0];
}

// ---------------- fused layer 1: h = x @ W1 (K=3) + hs/hd -------------------
__global__ __launch_bounds__(256) void k_layer1(const float* __restrict__ x,
                                                const float* __restrict__ W1,
                                                const float* __restrict__ as_,
                                                const float* __restrict__ ad_) {
    int lane = threadIdx.x & 63, wave = threadIdx.x >> 6;
    int row = blockIdx.x * 4 + wave;       // < B*N
    const float* xr = x + row * C;
    float x0 = xr[0], x1 = xr[1], x2 = xr[2];   // wave-uniform broadcast loads
    float* hr = g_hB + row * H;
    float vs = 0.f, vd = 0.f;
#pragma unroll
    for (int seg = 0; seg < 3; seg++) {
        int j = lane + seg * 64;
        if (j < H) {
            float h = x0 * W1[j] + x1 * W1[H + j] + x2 * W1[2 * H + j];
            hr[j] = h;
            vs += h * as_[j];
            vd += h * ad_[j];
        }
    }
#pragma unroll
    for (int d = 32; d > 0; d >>= 1) {
        vs += __shfl_xor(vs, d);
        vd += __shfl_xor(vd, d);
    }
    if (lane == 0) { g_hs[row] = vs; g_hd[row] = vd; }
}

// ---------------- split-precision MFMA GEMM + fused hs/hd -------------------
__global__ __launch_bounds__(1024, 1) void k_gemm_mfma(int layer, const float* __restrict__ as_,
                                                       const float* __restrict__ ad_) {
    __shared__ short lWhi[NFRAG * 8];   // 51200 B
    __shared__ short lWlo[NFRAG * 8];   // 51200 B
    int tid = threadIdx.x;
    int lane = tid & 63;

    {   // coalesced staging: 16B per thread per iteration
        const __hip_bfloat16* sh = g_Wfhi[layer];
        const __hip_bfloat16* sl = g_Wflo[layer];
        for (int i = tid; i < NFRAG; i += 1024) {
            *(bf16x8*)&lWhi[i * 8] = *(const bf16x8*)&sh[i * 8];
            *(bf16x8*)&lWlo[i * 8] = *(const bf16x8*)&sl[i * 8];
        }
    }
    __syncthreads();

    int row0 = blockIdx.x * 256 + (tid >> 6) * 16;   // one tile per wave
    const __hip_bfloat16* ah = &g_hAhi[row0 + (lane & 15)][0];
    const __hip_bfloat16* al = &g_hAlo[row0 + (lane & 15)][0];
    bf16x8 ahi[KS], alo[KS];
#pragma unroll
    for (int ks = 0; ks < KS; ks++) {
        ahi[ks] = *(const bf16x8*)&ah[ks * 32 + (lane >> 4) * 8];
        alo[ks] = *(const bf16x8*)&al[ks * 32 + (lane >> 4) * 8];
    }
    f32x4 acc[NT];
#pragma unroll
    for (int nt = 0; nt < NT; nt++) acc[nt] = (f32x4){0.f, 0.f, 0.f, 0.f};
#pragma unroll
    for (int ks = 0; ks < KS; ks++) {
#pragma unroll
        for (int nt = 0; nt < NT; nt++) {
            bf16x8 bh = *(bf16x8*)&lWhi[((nt * KS + ks) * 64 + lane) * 8];
            bf16x8 bl = *(bf16x8*)&lWlo[((nt * KS + ks) * 64 + lane) * 8];
            acc[nt] = __builtin_amdgcn_mfma_f32_16x16x32_bf16(ahi[ks], bh, acc[nt], 0, 0, 0);
            acc[nt] = __builtin_amdgcn_mfma_f32_16x16x32_bf16(alo[ks], bh, acc[nt], 0, 0, 0);
            acc[nt] = __builtin_amdgcn_mfma_f32_16x16x32_bf16(ahi[ks], bl, acc[nt], 0, 0, 0);
        }
    }

    // epilogue: D store + fused hs/hd (C/D: col=lane&15, row=(lane>>4)*4+reg)
    int col = lane & 15, rg = lane >> 4;
    float ps[4] = {0, 0, 0, 0}, pd[4] = {0, 0, 0, 0};
#pragma unroll
    for (int nt = 0; nt < NT; nt++) {
        int c = nt * 16 + col;
        bool ok = c < H;
        float asv = ok ? as_[c] : 0.f;
        float adv = ok ? ad_[c] : 0.f;
#pragma unroll
        for (int r = 0; r < 4; r++) {
            float v = acc[nt][r];
            if (ok) g_hB[(row0 + rg * 4 + r) * H + c] = v;
            ps[r] += v * asv;
            pd[r] += v * adv;
        }
    }
#pragma unroll
    for (int m = 1; m < 16; m <<= 1) {
#pragma unroll
        for (int r = 0; r < 4; r++) {
            ps[r] += __shfl_xor(ps[r], m);
            pd[r] += __shfl_xor(pd[r], m);
        }
    }
    if (col == 0) {
#pragma unroll
        for (int r = 0; r < 4; r++) {
            g_hs[row0 + rg * 4 + r] = ps[r];
            g_hd[row0 + rg * 4 + r] = pd[r];
        }
    }
}

// ---------------- edge softmax weights (normalized) -------------------------
// One wave per dst node; writes g_wgt[beg..end) = softmax weights.
__global__ __launch_bounds__(256) void k_edgew() {
    int lane = threadIdx.x & 63, wave = threadIdx.x >> 6;
    int p = blockIdx.x;
    int xcd = p & 7, slot = p >> 3;
    int b = xcd + 8 * (slot >> 8);
    int d = (slot & 255) * 4 + wave;
    int node = (b << 10) + d;

    int beg = g_offs[b * (N + 1) + d], end = g_offs[b * (N + 1) + d + 1];
    int deg = end - beg;
    const int* srcs = g_ssrc + b * EP;
    const float* hsb = g_hs + b * N;
    float* wgt = g_wgt + b * EP;
    float hdv = g_hd[node];

    if (deg <= 64) {
        float ev = -1e30f;
        if (lane < deg) {
            int sv = srcs[beg + lane];
            float e = hsb[sv] + hdv;
            ev = (e > 0.f) ? e : 0.2f * e;
        }
        float m = ev;
#pragma unroll
        for (int s = 32; s > 0; s >>= 1) m = fmaxf(m, __shfl_xor(m, s));
        float wv = (lane < deg) ? __expf(ev - m) : 0.f;
        float denom = wv;
#pragma unroll
        for (int s = 32; s > 0; s >>= 1) denom += __shfl_xor(denom, s);
        if (lane < deg) wgt[beg + lane] = wv / denom;
    } else {
        float m = -1e30f;
        for (int i = beg + lane; i < end; i += 64) {
            float e = hsb[srcs[i]] + hdv;
            e = (e > 0.f) ? e : 0.2f * e;
            m = fmaxf(m, e);
        }
#pragma unroll
        for (int s = 32; s > 0; s >>= 1) m = fmaxf(m, __shfl_xor(m, s));
        float denom = 0.f;
        for (int i = beg + lane; i < end; i += 64) {
            float e = hsb[srcs[i]] + hdv;
            e = (e > 0.f) ? e : 0.2f * e;
            denom += __expf(e - m);
        }
#pragma unroll
        for (int s = 32; s > 0; s >>= 1) denom += __shfl_xor(denom, s);
        float inv = 1.0f / denom;
        for (int i = beg + lane; i < end; i += 64) {
            float e = hsb[srcs[i]] + hdv;
            e = (e > 0.f) ? e : 0.2f * e;
            wgt[i] = __expf(e - m) * inv;
        }
    }
}

// ---------------- LDS-staged aggregation + pooling --------------------------
// Grid: chunk-major (chunk = bid>>6, graph = bid&63) so a graph's 5 chunks
// share one XCD's L2. Block: 1024 threads = 32 half-wave groups; group owns
// 32 cols (one chunk), sweeps 32 nodes; hB cols staged in LDS.
__global__ __launch_bounds__(1024, 1) void k_aggC(const float* __restrict__ bias, int pool_off) {
    __shared__ float hS[N][CCH];       // 131072 B
    __shared__ float pS[32][CCH];      // 4096 B
    int tid = threadIdx.x;
    int graph = blockIdx.x & 63;
    int chunk = blockIdx.x >> 6;
    int cl = tid & 31;
    int col = chunk * CCH + cl;
    int grp = tid >> 5;                // 0..31
    int sbase = (grp & 1) * 32;        // group's lane base within its wave

    // ---- stage hB[:, chunk cols] into LDS (coalesced) ----
    const float* hb = g_hB + graph * N * H;
    for (int r0 = 0; r0 < N; r0 += 32) {
        int row = r0 + grp;
        hS[row][cl] = (col < H) ? hb[row * H + col] : 0.f;
    }
    __syncthreads();

    const int* srcs = g_ssrc + graph * EP;
    const float* wgt = g_wgt + graph * EP;
    const int* offs = g_offs + graph * (N + 1);
    float bv = (col < H) ? bias[col] : 0.f;
    float pool = 0.f;

    for (int nn = 0; nn < 32; nn++) {
        int node = grp * 32 + nn;
        int beg = offs[node];
        int deg = offs[node + 1] - beg;
        float acc = 0.f;
        for (int base = 0; base < deg; base += 32) {
            int j = base + cl;
            int jj = (j < deg) ? j : (deg - 1);
            int es = srcs[beg + jj];
            float ew = (j < deg) ? wgt[beg + jj] : 0.f;
            int nb = deg - base; if (nb > 32) nb = 32;
            for (int i = 0; i < nb; i++) {
                int s = __shfl(es, sbase + i);
                float w = __shfl(ew, sbase + i);
                acc += w * hS[s][cl];
            }
        }
        int nd = graph * N + node;
        if (col < H) {
            float o = acc + bv;
            __hip_bfloat16 hi = __float2bfloat16(o);
            g_hAhi[nd][col] = hi;
            g_hAlo[nd][col] = __float2bfloat16(o - __bfloat162float(hi));
            pool += o;
        } else {                       // zero-pad cols 152..159 (chunk 4)
            g_hAhi[nd][col] = __float2bfloat16(0.f);
            g_hAlo[nd][col] = __float2bfloat16(0.f);
        }
    }

    // ---- pooled reduce across 32 groups ----
    pS[grp][cl] = pool;
    __syncthreads();
    for (int s = 16; s > 0; s >>= 1) {
        if (grp < s) pS[grp][cl] += pS[grp + s][cl];
        __syncthreads();
    }
    if (grp == 0 && col < H)
        atomicAdd(&g_pooled[graph * FC_IN + pool_off + col], pS[0][cl]);
}

// ---------------- MLP head ----------------
__global__ __launch_bounds__(256) void k_mlp(const float* __restrict__ fc1W, const float* __restrict__ fc1b,
                                             const float* __restrict__ fc2W, const float* __restrict__ fc2b,
                                             const float* __restrict__ fc3W, const float* __restrict__ fc3b,
                                             float* __restrict__ out) {
    int b = blockIdx.x, t = threadIdx.x;
    __shared__ float p[FC_IN];
    __shared__ float h1[256];
    __shared__ float h2[128];
    const float invN = 1.0f / N;
    for (int i = t; i < FC_IN; i += 256) p[i] = g_pooled[b * FC_IN + i] * invN;
    __syncthreads();
    float acc = fc1b[t];
    for (int k = 0; k < FC_IN; k++) acc += p[k] * fc1W[k * 256 + t];
    h1[t] = acc;
    __syncthreads();
    if (t < 128) {
        float a = fc2b[t];
        for (int k = 0; k < 256; k++) a += h1[k] * fc2W[k * 128 + t];
        h2[t] = a;
    }
    __syncthreads();
    if (t < NC) {
        float a = fc3b[t];
        for (int k = 0; k < 128; k++) a += h2[k] * fc3W[k * NC + t];
        out[b * NC + t] = a;
    }
}

// ---------------- launch ----------------
extern "C" void kernel_launch(void* const* d_in, const int* in_sizes, int n_in,
                              void* d_out, int out_size, void* d_ws, size_t ws_size,
                              hipStream_t stream) {
    const float* x    = (const float*)d_in[0];
    const int*   ei   = (const int*)d_in[1];
    const float* W1   = (const float*)d_in[2];
    const float* as1  = (const float*)d_in[3];
    const float* ad1  = (const float*)d_in[4];
    const float* b1   = (const float*)d_in[5];
    const float* W234 = (const float*)d_in[6];
    const float* as234= (const float*)d_in[7];
    const float* ad234= (const float*)d_in[8];
    const float* b234 = (const float*)d_in[9];
    const float* fc1W = (const float*)d_in[10];
    const float* fc1b = (const float*)d_in[11];
    const float* fc2W = (const float*)d_in[12];
    const float* fc2b = (const float*)d_in[13];
    const float* fc3W = (const float*)d_in[14];
    const float* fc3b = (const float*)d_in[15];
    float* out = (float*)d_out;

    hipLaunchKernelGGL(k_zero, dim3(256), dim3(256), 0, stream);
    hipLaunchKernelGGL(k_packW, dim3((3 * NFRAG * 8 + 255) / 256), dim3(256), 0, stream, W234);
    hipLaunchKernelGGL(k_count, dim3((B * E + 255) / 256), dim3(256), 0, stream, ei);
    hipLaunchKernelGGL(k_scan, dim3(B), dim3(1024), 0, stream);
    hipLaunchKernelGGL(k_scatter, dim3((B * E + 255) / 256), dim3(256), 0, stream, ei);
    hipLaunchKernelGGL(k_pool_x, dim3(B), dim3(256), 0, stream, x);

    // Layer 1: fused transform + hs/hd, then weights + LDS aggregate
    hipLaunchKernelGGL(k_layer1, dim3(B * N / 4), dim3(256), 0, stream, x, W1, as1, ad1);
    hipLaunchKernelGGL(k_edgew, dim3(B * N / 4), dim3(256), 0, stream);
    hipLaunchKernelGGL(k_aggC, dim3(B * NCHK), dim3(1024), 0, stream, b1, 3);

    // Layers 2-4: MFMA GEMM (fused hs/hd) + weights + LDS aggregate
    for (int l = 0; l < 3; l++) {
        hipLaunchKernelGGL(k_gemm_mfma, dim3(256), dim3(1024), 0, stream,
                           l, as234 + l * H, ad234 + l * H);
        hipLaunchKernelGGL(k_edgew, dim3(B * N / 4), dim3(256), 0, stream);
        hipLaunchKernelGGL(k_aggC, dim3(B * NCHK), dim3(1024), 0, stream,
                           b234 + l * H, 3 + H + l * H);
    }

    hipLaunchKernelGGL(k_mlp, dim3(B), dim3(256), 0, stream,
                       fc1W, fc1b, fc2W, fc2b, fc3W, fc3b, out);
}

// Round 11
// 596.041 us; speedup vs baseline: 1.3262x; 1.3262x over previous
//
#include <hip/hip_runtime.h>
#include <hip/hip_bf16.h>

#define B 64
#define N 1024
#define E 8192
#define EP (E + N)      // 9216 edges incl self-loops
#define C 3
#define H 152
#define NC 10
#define FC_IN 611       // C + 4*H
#define KP 160          // padded H (5 * 32)
#define NT 10           // n-tiles of 16
#define KS 5            // k-steps of 32
#define NFRAG (NT * KS * 64)   // 3200 fragments of 8 bf16

typedef __attribute__((ext_vector_type(8))) short bf16x8;
typedef __attribute__((ext_vector_type(4))) float f32x4;

// ---------------- static scratch ----------------
__device__ __hip_bfloat16 g_hAhi[B * N][KP];       // layer outputs hi (bf16, padded)
__device__ __hip_bfloat16 g_hAlo[B * N][KP];       // layer outputs lo residual
__device__ __hip_bfloat16 g_hBb[B * N][H];         // transformed features (bf16)
__device__ float g_hs[B * N];
__device__ float g_hd[B * N];
__device__ float g_pooled[B * FC_IN];
__device__ __hip_bfloat16 g_Wfhi[3][NFRAG * 8];    // W^T hi, fragment-ordered
__device__ __hip_bfloat16 g_Wflo[3][NFRAG * 8];    // W^T lo, fragment-ordered
__device__ int   g_cnt[B * N];
__device__ int   g_woff[B * N];
__device__ int   g_offs[B * (N + 1)];
__device__ int   g_ssrc[B * EP];

// ---------------- init ----------------
__global__ void k_zero() {
    int i = blockIdx.x * blockDim.x + threadIdx.x;
    if (i < B * N) g_cnt[i] = 0;
    if (i < B * FC_IN) g_pooled[i] = 0.f;
}

// pack W^T split into MFMA-fragment order:
// frag i (= (nt*KS+ks)*64 + ln): elem j = W[(ks*32+(ln>>4)*8+j)][nt*16+(ln&15)]
__global__ void k_packW(const float* __restrict__ W234) {
    int gid = blockIdx.x * 256 + threadIdx.x;
    if (gid >= 3 * NFRAG * 8) return;
    int l = gid / (NFRAG * 8);
    int rem = gid - l * (NFRAG * 8);
    int i = rem >> 3, j = rem & 7;
    int frag = i >> 6, ln = i & 63;
    int nt = frag / KS, ks = frag - nt * KS;
    int n = nt * 16 + (ln & 15);
    int kk = ks * 32 + (ln >> 4) * 8 + j;
    float v = (n < H && kk < H) ? W234[(l * H + kk) * H + n] : 0.f;
    __hip_bfloat16 hi = __float2bfloat16(v);
    float lo = v - __bfloat162float(hi);
    g_Wfhi[l][rem] = hi;
    g_Wflo[l][rem] = __float2bfloat16(lo);
}

// ---------------- CSR build ----------------
__global__ void k_count(const int* __restrict__ ei) {
    int gid = blockIdx.x * 256 + threadIdx.x;
    if (gid >= B * E) return;
    int b = gid >> 13;
    int e = gid & (E - 1);
    int dst = ei[b * 2 * E + E + e];
    atomicAdd(&g_cnt[b * N + dst], 1);
}

__global__ __launch_bounds__(1024) void k_scan() {
    int b = blockIdx.x, t = threadIdx.x;
    __shared__ int s[N];
    int v = g_cnt[b * N + t] + 1;          // +1 self loop
    s[t] = v;
    __syncthreads();
    for (int d = 1; d < N; d <<= 1) {
        int add = (t >= d) ? s[t - d] : 0;
        __syncthreads();
        s[t] += add;
        __syncthreads();
    }
    int incl = s[t], excl = incl - v;
    g_offs[b * (N + 1) + t + 1] = incl;
    if (t == 0) g_offs[b * (N + 1)] = 0;
    g_ssrc[b * EP + excl] = t;             // self loop first in bucket
    g_woff[b * N + t] = excl + 1;
}

__global__ void k_scatter(const int* __restrict__ ei) {
    int gid = blockIdx.x * 256 + threadIdx.x;
    if (gid >= B * E) return;
    int b = gid >> 13;
    int e = gid & (E - 1);
    int src = ei[b * 2 * E + e];
    int dst = ei[b * 2 * E + E + e];
    int pos = atomicAdd(&g_woff[b * N + dst], 1);
    g_ssrc[b * EP + pos] = src;
}

// ---------------- x pooling ----------------
__global__ void k_pool_x(const float* __restrict__ x) {
    int b = blockIdx.x, t = threadIdx.x;
    float a0 = 0, a1 = 0, a2 = 0;
    for (int n = t; n < N; n += 256) {
        const float* p = x + (b * N + n) * C;
        a0 += p[0]; a1 += p[1]; a2 += p[2];
    }
    __shared__ float s[3][256];
    s[0][t] = a0; s[1][t] = a1; s[2][t] = a2;
    __syncthreads();
    for (int d = 128; d > 0; d >>= 1) {
        if (t < d) {
            s[0][t] += s[0][t + d];
            s[1][t] += s[1][t + d];
            s[2][t] += s[2][t + d];
        }
        __syncthreads();
    }
    if (t < 3) g_pooled[b * FC_IN + t] = s[t][0];
}

// ---------------- fused layer 1: h = x @ W1 (K=3) + hs/hd -------------------
// hs/hd computed from f32 h (pre-rounding); hB stored bf16.
__global__ __launch_bounds__(256) void k_layer1(const float* __restrict__ x,
                                                const float* __restrict__ W1,
                                                const float* __restrict__ as_,
                                                const float* __restrict__ ad_) {
    int lane = threadIdx.x & 63, wave = threadIdx.x >> 6;
    int row = blockIdx.x * 4 + wave;       // < B*N
    const float* xr = x + row * C;
    float x0 = xr[0], x1 = xr[1], x2 = xr[2];   // wave-uniform broadcast loads
    __hip_bfloat16* hr = &g_hBb[row][0];
    float vs = 0.f, vd = 0.f;
#pragma unroll
    for (int seg = 0; seg < 3; seg++) {
        int j = lane + seg * 64;
        if (j < H) {
            float h = x0 * W1[j] + x1 * W1[H + j] + x2 * W1[2 * H + j];
            hr[j] = __float2bfloat16(h);
            vs += h * as_[j];
            vd += h * ad_[j];
        }
    }
#pragma unroll
    for (int d = 32; d > 0; d >>= 1) {
        vs += __shfl_xor(vs, d);
        vd += __shfl_xor(vd, d);
    }
    if (lane == 0) { g_hs[row] = vs; g_hd[row] = vd; }
}

// ---------------- split-precision MFMA GEMM + fused hs/hd -------------------
// C = (Ahi+Alo) @ (Whi+Wlo) ~= Ahi*Whi + Alo*Whi + Ahi*Wlo   (f32 accumulate)
// 256 blocks x 1024 threads (16 waves = 4/SIMD): stage frag-ordered Whi+Wlo
// ONCE (coalesced linear copy) into 100KB LDS; one 16-row tile per wave.
// hs/hd from f32 acc; hB stored bf16.
__global__ __launch_bounds__(1024, 1) void k_gemm_mfma(int layer, const float* __restrict__ as_,
                                                       const float* __restrict__ ad_) {
    __shared__ short lWhi[NFRAG * 8];   // 51200 B
    __shared__ short lWlo[NFRAG * 8];   // 51200 B
    int tid = threadIdx.x;
    int lane = tid & 63;

    {   // coalesced staging: 16B per thread per iteration
        const __hip_bfloat16* sh = g_Wfhi[layer];
        const __hip_bfloat16* sl = g_Wflo[layer];
        for (int i = tid; i < NFRAG; i += 1024) {
            *(bf16x8*)&lWhi[i * 8] = *(const bf16x8*)&sh[i * 8];
            *(bf16x8*)&lWlo[i * 8] = *(const bf16x8*)&sl[i * 8];
        }
    }
    __syncthreads();

    int row0 = blockIdx.x * 256 + (tid >> 6) * 16;   // one tile per wave
    const __hip_bfloat16* ah = &g_hAhi[row0 + (lane & 15)][0];
    const __hip_bfloat16* al = &g_hAlo[row0 + (lane & 15)][0];
    bf16x8 ahi[KS], alo[KS];
#pragma unroll
    for (int ks = 0; ks < KS; ks++) {
        ahi[ks] = *(const bf16x8*)&ah[ks * 32 + (lane >> 4) * 8];
        alo[ks] = *(const bf16x8*)&al[ks * 32 + (lane >> 4) * 8];
    }
    f32x4 acc[NT];
#pragma unroll
    for (int nt = 0; nt < NT; nt++) acc[nt] = (f32x4){0.f, 0.f, 0.f, 0.f};
#pragma unroll
    for (int ks = 0; ks < KS; ks++) {
#pragma unroll
        for (int nt = 0; nt < NT; nt++) {
            bf16x8 bh = *(bf16x8*)&lWhi[((nt * KS + ks) * 64 + lane) * 8];
            bf16x8 bl = *(bf16x8*)&lWlo[((nt * KS + ks) * 64 + lane) * 8];
            acc[nt] = __builtin_amdgcn_mfma_f32_16x16x32_bf16(ahi[ks], bh, acc[nt], 0, 0, 0);
            acc[nt] = __builtin_amdgcn_mfma_f32_16x16x32_bf16(alo[ks], bh, acc[nt], 0, 0, 0);
            acc[nt] = __builtin_amdgcn_mfma_f32_16x16x32_bf16(ahi[ks], bl, acc[nt], 0, 0, 0);
        }
    }

    // epilogue: bf16 D store + fused hs/hd (C/D: col=lane&15, row=(lane>>4)*4+reg)
    int col = lane & 15, rg = lane >> 4;
    float ps[4] = {0, 0, 0, 0}, pd[4] = {0, 0, 0, 0};
#pragma unroll
    for (int nt = 0; nt < NT; nt++) {
        int c = nt * 16 + col;
        bool ok = c < H;
        float asv = ok ? as_[c] : 0.f;
        float adv = ok ? ad_[c] : 0.f;
#pragma unroll
        for (int r = 0; r < 4; r++) {
            float v = acc[nt][r];
            if (ok) g_hBb[row0 + rg * 4 + r][c] = __float2bfloat16(v);
            ps[r] += v * asv;
            pd[r] += v * adv;
        }
    }
#pragma unroll
    for (int m = 1; m < 16; m <<= 1) {
#pragma unroll
        for (int r = 0; r < 4; r++) {
            ps[r] += __shfl_xor(ps[r], m);
            pd[r] += __shfl_xor(pd[r], m);
        }
    }
    if (col == 0) {
#pragma unroll
        for (int r = 0; r < 4; r++) {
            g_hs[row0 + rg * 4 + r] = ps[r];
            g_hd[row0 + rg * 4 + r] = pd[r];
        }
    }
}

// ---------------- edge softmax + aggregation + fused pooling ----------------
// One wave per dst node; lane-parallel softmax; XCD-swizzled blocks;
// bf16 gather source (half the bytes/lines of f32);
// pooled sums reduced in LDS then one atomicAdd per feature per block.
__global__ __launch_bounds__(256) void k_aggregate(const float* __restrict__ bias, int pool_off) {
    int lane = threadIdx.x & 63, wave = threadIdx.x >> 6;
    // XCD swizzle: each XCD gets 8 whole graphs, graph-sequential
    int p = blockIdx.x;
    int xcd = p & 7, slot = p >> 3;
    int b = xcd + 8 * (slot >> 8);         // graph
    int d = (slot & 255) * 4 + wave;       // node within graph
    int node = (b << 10) + d;

    int beg = g_offs[b * (N + 1) + d], end = g_offs[b * (N + 1) + d + 1];
    int deg = end - beg;
    const int* srcs = g_ssrc + b * EP;
    const float* hsb = g_hs + b * N;
    const __hip_bfloat16* hb = &g_hBb[b * N][0];
    float hdv = g_hd[node];

    float a0 = 0.f, a1 = 0.f, a2 = 0.f;
    float denom;

    if (deg <= 64) {
        // ---- lane-parallel softmax over edges ----
        int sv = 0;
        float ev = -1e30f;
        if (lane < deg) {
            sv = srcs[beg + lane];
            float e = hsb[sv] + hdv;
            ev = (e > 0.f) ? e : 0.2f * e;
        }
        float m = ev;
#pragma unroll
        for (int s = 32; s > 0; s >>= 1) m = fmaxf(m, __shfl_xor(m, s));
        float wv = (lane < deg) ? __expf(ev - m) : 0.f;
        denom = wv;
#pragma unroll
        for (int s = 32; s > 0; s >>= 1) denom += __shfl_xor(denom, s);

        // ---- broadcast weighted gather, unroll x2, dual accumulators ----
        float b0 = 0.f, b1 = 0.f, b2 = 0.f;
        int i = 0;
        for (; i + 2 <= deg; i += 2) {
            int s0 = __shfl(sv, i), s1 = __shfl(sv, i + 1);
            float w0 = __shfl(wv, i), w1 = __shfl(wv, i + 1);
            const __hip_bfloat16* r0 = hb + s0 * H;
            const __hip_bfloat16* r1 = hb + s1 * H;
            float x00 = __bfloat162float(r0[lane]);
            float x01 = __bfloat162float(r0[lane + 64]);
            float x10 = __bfloat162float(r1[lane]);
            float x11 = __bfloat162float(r1[lane + 64]);
            float x02 = 0.f, x12 = 0.f;
            if (lane < H - 128) {
                x02 = __bfloat162float(r0[lane + 128]);
                x12 = __bfloat162float(r1[lane + 128]);
            }
            a0 += w0 * x00; a1 += w0 * x01; a2 += w0 * x02;
            b0 += w1 * x10; b1 += w1 * x11; b2 += w1 * x12;
        }
        if (i < deg) {
            int s0 = __shfl(sv, i);
            float w0 = __shfl(wv, i);
            const __hip_bfloat16* r0 = hb + s0 * H;
            a0 += w0 * __bfloat162float(r0[lane]);
            a1 += w0 * __bfloat162float(r0[lane + 64]);
            if (lane < H - 128) a2 += w0 * __bfloat162float(r0[lane + 128]);
        }
        a0 += b0; a1 += b1; a2 += b2;
    } else {
        // ---- fallback: serial two-pass (correct for any degree) ----
        float m = -1e30f;
        for (int i = beg; i < end; i++) {
            float e = hsb[srcs[i]] + hdv;
            e = (e > 0.f) ? e : 0.2f * e;
            m = fmaxf(m, e);
        }
        denom = 0.f;
        for (int i = beg; i < end; i++) {
            int s = srcs[i];
            float e = hsb[s] + hdv;
            e = (e > 0.f) ? e : 0.2f * e;
            float w = __expf(e - m);
            denom += w;
            const __hip_bfloat16* hr = hb + s * H;
            a0 += w * __bfloat162float(hr[lane]);
            a1 += w * __bfloat162float(hr[lane + 64]);
            if (lane < H - 128) a2 += w * __bfloat162float(hr[lane + 128]);
        }
    }

    float inv = 1.0f / denom;
    __hip_bfloat16* hrow = &g_hAhi[node][0];
    __hip_bfloat16* lrow = &g_hAlo[node][0];
    float o0 = a0 * inv + bias[lane];
    float o1 = a1 * inv + bias[lane + 64];
    float o2 = 0.f;
    __hip_bfloat16 h0 = __float2bfloat16(o0);
    __hip_bfloat16 h1 = __float2bfloat16(o1);
    hrow[lane] = h0;      lrow[lane] = __float2bfloat16(o0 - __bfloat162float(h0));
    hrow[lane + 64] = h1; lrow[lane + 64] = __float2bfloat16(o1 - __bfloat162float(h1));
    if (lane < H - 128) {
        o2 = a2 * inv + bias[lane + 128];
        __hip_bfloat16 h2 = __float2bfloat16(o2);
        hrow[lane + 128] = h2;
        lrow[lane + 128] = __float2bfloat16(o2 - __bfloat162float(h2));
    }
    if (lane < KP - H) {   // zero pad cols 152..159
        hrow[H + lane] = __float2bfloat16(0.f);
        lrow[H + lane] = __float2bfloat16(0.f);
    }

    // ---- fused pooling: block-level LDS reduce, then global atomics ----
    __shared__ float sp[3][64];
    if (wave == 0) { sp[0][lane] = 0.f; sp[1][lane] = 0.f; sp[2][lane] = 0.f; }
    __syncthreads();
    atomicAdd(&sp[0][lane], o0);
    atomicAdd(&sp[1][lane], o1);
    if (lane < H - 128) atomicAdd(&sp[2][lane], o2);
    __syncthreads();
    if (wave == 0) {
        float* pb = g_pooled + b * FC_IN + pool_off;
        atomicAdd(&pb[lane], sp[0][lane]);
        atomicAdd(&pb[lane + 64], sp[1][lane]);
        if (lane < H - 128) atomicAdd(&pb[lane + 128], sp[2][lane]);
    }
}

// ---------------- MLP head ----------------
__global__ __launch_bounds__(256) void k_mlp(const float* __restrict__ fc1W, const float* __restrict__ fc1b,
                                             const float* __restrict__ fc2W, const float* __restrict__ fc2b,
                                             const float* __restrict__ fc3W, const float* __restrict__ fc3b,
                                             float* __restrict__ out) {
    int b = blockIdx.x, t = threadIdx.x;
    __shared__ float p[FC_IN];
    __shared__ float h1[256];
    __shared__ float h2[128];
    const float invN = 1.0f / N;
    for (int i = t; i < FC_IN; i += 256) p[i] = g_pooled[b * FC_IN + i] * invN;
    __syncthreads();
    float acc = fc1b[t];
    for (int k = 0; k < FC_IN; k++) acc += p[k] * fc1W[k * 256 + t];
    h1[t] = acc;
    __syncthreads();
    if (t < 128) {
        float a = fc2b[t];
        for (int k = 0; k < 256; k++) a += h1[k] * fc2W[k * 128 + t];
        h2[t] = a;
    }
    __syncthreads();
    if (t < NC) {
        float a = fc3b[t];
        for (int k = 0; k < 128; k++) a += h2[k] * fc3W[k * NC + t];
        out[b * NC + t] = a;
    }
}

// ---------------- launch ----------------
extern "C" void kernel_launch(void* const* d_in, const int* in_sizes, int n_in,
                              void* d_out, int out_size, void* d_ws, size_t ws_size,
                              hipStream_t stream) {
    const float* x    = (const float*)d_in[0];
    const int*   ei   = (const int*)d_in[1];
    const float* W1   = (const float*)d_in[2];
    const float* as1  = (const float*)d_in[3];
    const float* ad1  = (const float*)d_in[4];
    const float* b1   = (const float*)d_in[5];
    const float* W234 = (const float*)d_in[6];
    const float* as234= (const float*)d_in[7];
    const float* ad234= (const float*)d_in[8];
    const float* b234 = (const float*)d_in[9];
    const float* fc1W = (const float*)d_in[10];
    const float* fc1b = (const float*)d_in[11];
    const float* fc2W = (const float*)d_in[12];
    const float* fc2b = (const float*)d_in[13];
    const float* fc3W = (const float*)d_in[14];
    const float* fc3b = (const float*)d_in[15];
    float* out = (float*)d_out;

    hipLaunchKernelGGL(k_zero, dim3(256), dim3(256), 0, stream);
    hipLaunchKernelGGL(k_packW, dim3((3 * NFRAG * 8 + 255) / 256), dim3(256), 0, stream, W234);
    hipLaunchKernelGGL(k_count, dim3((B * E + 255) / 256), dim3(256), 0, stream, ei);
    hipLaunchKernelGGL(k_scan, dim3(B), dim3(1024), 0, stream);
    hipLaunchKernelGGL(k_scatter, dim3((B * E + 255) / 256), dim3(256), 0, stream, ei);
    hipLaunchKernelGGL(k_pool_x, dim3(B), dim3(256), 0, stream, x);

    // Layer 1: fused transform + hs/hd, then aggregate(+pool)
    hipLaunchKernelGGL(k_layer1, dim3(B * N / 4), dim3(256), 0, stream, x, W1, as1, ad1);
    hipLaunchKernelGGL(k_aggregate, dim3(B * N / 4), dim3(256), 0, stream, b1, 3);

    // Layers 2-4: split-precision MFMA GEMM (fused hs/hd) + aggregate(+pool)
    for (int l = 0; l < 3; l++) {
        hipLaunchKernelGGL(k_gemm_mfma, dim3(256), dim3(1024), 0, stream,
                           l, as234 + l * H, ad234 + l * H);
        hipLaunchKernelGGL(k_aggregate, dim3(B * N / 4), dim3(256), 0, stream,
                           b234 + l * H, 3 + H + l * H);
    }

    hipLaunchKernelGGL(k_mlp, dim3(B), dim3(256), 0, stream,
                       fc1W, fc1b, fc2W, fc2b, fc3W, fc3b, out);
}

// Round 12
// 577.670 us; speedup vs baseline: 1.3684x; 1.0318x over previous
//
#include <hip/hip_runtime.h>
#include <hip/hip_bf16.h>

#define B 64
#define N 1024
#define E 8192
#define EP (E + N)      // 9216 edges incl self-loops
#define C 3
#define H 152
#define NC 10
#define FC_IN 611       // C + 4*H
#define KP 160          // padded H (5 * 32)
#define NT 10           // n-tiles of 16
#define KS 5            // k-steps of 32
#define NFRAG (NT * KS * 64)   // 3200 fragments of 8 bf16
#define TSTRIDE (KS * 64 * 8)  // 2560 elements per 16-row A-tile

typedef __attribute__((ext_vector_type(8))) short bf16x8;
typedef __attribute__((ext_vector_type(4))) float f32x4;

// ---------------- static scratch ----------------
// A operand (layer outputs) in MFMA-fragment-packed order:
// [tile][ks][lane][j]: lane l holds row (l&15), k = ks*32 + (l>>4)*8 + j
__device__ __hip_bfloat16 g_hAfhi[(B * N / 16) * TSTRIDE];
__device__ __hip_bfloat16 g_hAflo[(B * N / 16) * TSTRIDE];
__device__ __hip_bfloat16 g_hBb[B * N][H];         // transformed features (bf16)
__device__ float g_hs[B * N];
__device__ float g_hd[B * N];
__device__ float g_pooled[B * FC_IN];
__device__ __hip_bfloat16 g_Wfhi[3][NFRAG * 8];    // W^T hi, fragment-ordered
__device__ __hip_bfloat16 g_Wflo[3][NFRAG * 8];    // W^T lo, fragment-ordered
__device__ int   g_cnt[B * N];
__device__ int   g_woff[B * N];
__device__ int   g_offs[B * (N + 1)];
__device__ int   g_ssrc[B * EP];

// ---------------- init ----------------
__global__ void k_zero() {
    int i = blockIdx.x * blockDim.x + threadIdx.x;
    if (i < B * N) g_cnt[i] = 0;
    if (i < B * FC_IN) g_pooled[i] = 0.f;
}

// pack W^T split into MFMA-fragment order:
// frag i (= (nt*KS+ks)*64 + ln): elem j = W[(ks*32+(ln>>4)*8+j)][nt*16+(ln&15)]
__global__ void k_packW(const float* __restrict__ W234) {
    int gid = blockIdx.x * 256 + threadIdx.x;
    if (gid >= 3 * NFRAG * 8) return;
    int l = gid / (NFRAG * 8);
    int rem = gid - l * (NFRAG * 8);
    int i = rem >> 3, j = rem & 7;
    int frag = i >> 6, ln = i & 63;
    int nt = frag / KS, ks = frag - nt * KS;
    int n = nt * 16 + (ln & 15);
    int kk = ks * 32 + (ln >> 4) * 8 + j;
    float v = (n < H && kk < H) ? W234[(l * H + kk) * H + n] : 0.f;
    __hip_bfloat16 hi = __float2bfloat16(v);
    float lo = v - __bfloat162float(hi);
    g_Wfhi[l][rem] = hi;
    g_Wflo[l][rem] = __float2bfloat16(lo);
}

// ---------------- CSR build ----------------
__global__ void k_count(const int* __restrict__ ei) {
    int gid = blockIdx.x * 256 + threadIdx.x;
    if (gid >= B * E) return;
    int b = gid >> 13;
    int e = gid & (E - 1);
    int dst = ei[b * 2 * E + E + e];
    atomicAdd(&g_cnt[b * N + dst], 1);
}

__global__ __launch_bounds__(1024) void k_scan() {
    int b = blockIdx.x, t = threadIdx.x;
    __shared__ int s[N];
    int v = g_cnt[b * N + t] + 1;          // +1 self loop
    s[t] = v;
    __syncthreads();
    for (int d = 1; d < N; d <<= 1) {
        int add = (t >= d) ? s[t - d] : 0;
        __syncthreads();
        s[t] += add;
        __syncthreads();
    }
    int incl = s[t], excl = incl - v;
    g_offs[b * (N + 1) + t + 1] = incl;
    if (t == 0) g_offs[b * (N + 1)] = 0;
    g_ssrc[b * EP + excl] = t;             // self loop first in bucket
    g_woff[b * N + t] = excl + 1;
}

__global__ void k_scatter(const int* __restrict__ ei) {
    int gid = blockIdx.x * 256 + threadIdx.x;
    if (gid >= B * E) return;
    int b = gid >> 13;
    int e = gid & (E - 1);
    int src = ei[b * 2 * E + e];
    int dst = ei[b * 2 * E + E + e];
    int pos = atomicAdd(&g_woff[b * N + dst], 1);
    g_ssrc[b * EP + pos] = src;
}

// ---------------- x pooling ----------------
__global__ void k_pool_x(const float* __restrict__ x) {
    int b = blockIdx.x, t = threadIdx.x;
    float a0 = 0, a1 = 0, a2 = 0;
    for (int n = t; n < N; n += 256) {
        const float* p = x + (b * N + n) * C;
        a0 += p[0]; a1 += p[1]; a2 += p[2];
    }
    __shared__ float s[3][256];
    s[0][t] = a0; s[1][t] = a1; s[2][t] = a2;
    __syncthreads();
    for (int d = 128; d > 0; d >>= 1) {
        if (t < d) {
            s[0][t] += s[0][t + d];
            s[1][t] += s[1][t + d];
            s[2][t] += s[2][t + d];
        }
        __syncthreads();
    }
    if (t < 3) g_pooled[b * FC_IN + t] = s[t][0];
}

// ---------------- fused layer 1: h = x @ W1 (K=3) + hs/hd -------------------
__global__ __launch_bounds__(256) void k_layer1(const float* __restrict__ x,
                                                const float* __restrict__ W1,
                                                const float* __restrict__ as_,
                                                const float* __restrict__ ad_) {
    int lane = threadIdx.x & 63, wave = threadIdx.x >> 6;
    int row = blockIdx.x * 4 + wave;       // < B*N
    const float* xr = x + row * C;
    float x0 = xr[0], x1 = xr[1], x2 = xr[2];   // wave-uniform broadcast loads
    __hip_bfloat16* hr = &g_hBb[row][0];
    float vs = 0.f, vd = 0.f;
#pragma unroll
    for (int seg = 0; seg < 3; seg++) {
        int j = lane + seg * 64;
        if (j < H) {
            float h = x0 * W1[j] + x1 * W1[H + j] + x2 * W1[2 * H + j];
            hr[j] = __float2bfloat16(h);
            vs += h * as_[j];
            vd += h * ad_[j];
        }
    }
#pragma unroll
    for (int d = 32; d > 0; d >>= 1) {
        vs += __shfl_xor(vs, d);
        vd += __shfl_xor(vd, d);
    }
    if (lane == 0) { g_hs[row] = vs; g_hd[row] = vd; }
}

// ---------------- split-precision MFMA GEMM + fused hs/hd -------------------
// C = (Ahi+Alo) @ (Whi+Wlo) ~= Ahi*Whi + Alo*Whi + Ahi*Wlo   (f32 accumulate)
// 256 blocks x 1024 threads: stage frag-ordered Whi+Wlo once into 100KB LDS;
// one 16-row tile per wave; A reads are coalesced 1KB fragment loads.
__global__ __launch_bounds__(1024, 1) void k_gemm_mfma(int layer, const float* __restrict__ as_,
                                                       const float* __restrict__ ad_) {
    __shared__ short lWhi[NFRAG * 8];   // 51200 B
    __shared__ short lWlo[NFRAG * 8];   // 51200 B
    int tid = threadIdx.x;
    int lane = tid & 63;

    {   // coalesced staging: 16B per thread per iteration
        const __hip_bfloat16* sh = g_Wfhi[layer];
        const __hip_bfloat16* sl = g_Wflo[layer];
        for (int i = tid; i < NFRAG; i += 1024) {
            *(bf16x8*)&lWhi[i * 8] = *(const bf16x8*)&sh[i * 8];
            *(bf16x8*)&lWlo[i * 8] = *(const bf16x8*)&sl[i * 8];
        }
    }
    __syncthreads();

    int tile = blockIdx.x * 16 + (tid >> 6);         // one 16-row tile per wave
    int row0 = tile * 16;
    const __hip_bfloat16* fh = &g_hAfhi[tile * TSTRIDE];
    const __hip_bfloat16* fl = &g_hAflo[tile * TSTRIDE];
    bf16x8 ahi[KS], alo[KS];
#pragma unroll
    for (int ks = 0; ks < KS; ks++) {
        ahi[ks] = *(const bf16x8*)&fh[ks * 512 + lane * 8];   // coalesced 1KB
        alo[ks] = *(const bf16x8*)&fl[ks * 512 + lane * 8];
    }
    f32x4 acc[NT];
#pragma unroll
    for (int nt = 0; nt < NT; nt++) acc[nt] = (f32x4){0.f, 0.f, 0.f, 0.f};
#pragma unroll
    for (int ks = 0; ks < KS; ks++) {
#pragma unroll
        for (int nt = 0; nt < NT; nt++) {
            bf16x8 bh = *(bf16x8*)&lWhi[((nt * KS + ks) * 64 + lane) * 8];
            bf16x8 bl = *(bf16x8*)&lWlo[((nt * KS + ks) * 64 + lane) * 8];
            acc[nt] = __builtin_amdgcn_mfma_f32_16x16x32_bf16(ahi[ks], bh, acc[nt], 0, 0, 0);
            acc[nt] = __builtin_amdgcn_mfma_f32_16x16x32_bf16(alo[ks], bh, acc[nt], 0, 0, 0);
            acc[nt] = __builtin_amdgcn_mfma_f32_16x16x32_bf16(ahi[ks], bl, acc[nt], 0, 0, 0);
        }
    }

    // epilogue: bf16 D store + fused hs/hd (C/D: col=lane&15, row=(lane>>4)*4+reg)
    int col = lane & 15, rg = lane >> 4;
    float ps[4] = {0, 0, 0, 0}, pd[4] = {0, 0, 0, 0};
#pragma unroll
    for (int nt = 0; nt < NT; nt++) {
        int c = nt * 16 + col;
        bool ok = c < H;
        float asv = ok ? as_[c] : 0.f;
        float adv = ok ? ad_[c] : 0.f;
#pragma unroll
        for (int r = 0; r < 4; r++) {
            float v = acc[nt][r];
            if (ok) g_hBb[row0 + rg * 4 + r][c] = __float2bfloat16(v);
            ps[r] += v * asv;
            pd[r] += v * adv;
        }
    }
#pragma unroll
    for (int m = 1; m < 16; m <<= 1) {
#pragma unroll
        for (int r = 0; r < 4; r++) {
            ps[r] += __shfl_xor(ps[r], m);
            pd[r] += __shfl_xor(pd[r], m);
        }
    }
    if (col == 0) {
#pragma unroll
        for (int r = 0; r < 4; r++) {
            g_hs[row0 + rg * 4 + r] = ps[r];
            g_hd[row0 + rg * 4 + r] = pd[r];
        }
    }
}

// ---------------- edge softmax + aggregation + fused pooling ----------------
// One wave per dst node; lane-parallel softmax; XCD-swizzled blocks; bf16
// gather; 4-way unrolled gather; output stored in MFMA-fragment-packed order.
__global__ __launch_bounds__(256) void k_aggregate(const float* __restrict__ bias, int pool_off) {
    int lane = threadIdx.x & 63, wave = threadIdx.x >> 6;
    // XCD swizzle: each XCD gets 8 whole graphs, graph-sequential
    int p = blockIdx.x;
    int xcd = p & 7, slot = p >> 3;
    int b = xcd + 8 * (slot >> 8);         // graph
    int d = (slot & 255) * 4 + wave;       // node within graph
    int node = (b << 10) + d;

    int beg = g_offs[b * (N + 1) + d], end = g_offs[b * (N + 1) + d + 1];
    int deg = end - beg;
    const int* srcs = g_ssrc + b * EP;
    const float* hsb = g_hs + b * N;
    const __hip_bfloat16* hb = &g_hBb[b * N][0];
    float hdv = g_hd[node];

    float a0 = 0.f, a1 = 0.f, a2 = 0.f;
    float denom;

    if (deg <= 64) {
        // ---- lane-parallel softmax over edges ----
        int sv = 0;
        float ev = -1e30f;
        if (lane < deg) {
            sv = srcs[beg + lane];
            float e = hsb[sv] + hdv;
            ev = (e > 0.f) ? e : 0.2f * e;
        }
        float m = ev;
#pragma unroll
        for (int s = 32; s > 0; s >>= 1) m = fmaxf(m, __shfl_xor(m, s));
        float wv = (lane < deg) ? __expf(ev - m) : 0.f;
        denom = wv;
#pragma unroll
        for (int s = 32; s > 0; s >>= 1) denom += __shfl_xor(denom, s);

        // ---- broadcast weighted gather: 4-way unroll, 4 accumulator sets ----
        float b0 = 0.f, b1 = 0.f, b2 = 0.f;
        float c0 = 0.f, c1 = 0.f, c2 = 0.f;
        float e0 = 0.f, e1 = 0.f, e2 = 0.f;
        int i = 0;
        for (; i + 4 <= deg; i += 4) {
            int s0 = __shfl(sv, i),     s1 = __shfl(sv, i + 1);
            int s2 = __shfl(sv, i + 2), s3 = __shfl(sv, i + 3);
            float w0 = __shfl(wv, i),     w1 = __shfl(wv, i + 1);
            float w2 = __shfl(wv, i + 2), w3 = __shfl(wv, i + 3);
            const __hip_bfloat16* r0 = hb + s0 * H;
            const __hip_bfloat16* r1 = hb + s1 * H;
            const __hip_bfloat16* r2 = hb + s2 * H;
            const __hip_bfloat16* r3 = hb + s3 * H;
            float x00 = __bfloat162float(r0[lane]);
            float x01 = __bfloat162float(r0[lane + 64]);
            float x10 = __bfloat162float(r1[lane]);
            float x11 = __bfloat162float(r1[lane + 64]);
            float x20 = __bfloat162float(r2[lane]);
            float x21 = __bfloat162float(r2[lane + 64]);
            float x30 = __bfloat162float(r3[lane]);
            float x31 = __bfloat162float(r3[lane + 64]);
            float x02 = 0.f, x12 = 0.f, x22 = 0.f, x32 = 0.f;
            if (lane < H - 128) {
                x02 = __bfloat162float(r0[lane + 128]);
                x12 = __bfloat162float(r1[lane + 128]);
                x22 = __bfloat162float(r2[lane + 128]);
                x32 = __bfloat162float(r3[lane + 128]);
            }
            a0 += w0 * x00; a1 += w0 * x01; a2 += w0 * x02;
            b0 += w1 * x10; b1 += w1 * x11; b2 += w1 * x12;
            c0 += w2 * x20; c1 += w2 * x21; c2 += w2 * x22;
            e0 += w3 * x30; e1 += w3 * x31; e2 += w3 * x32;
        }
        for (; i + 2 <= deg; i += 2) {
            int s0 = __shfl(sv, i), s1 = __shfl(sv, i + 1);
            float w0 = __shfl(wv, i), w1 = __shfl(wv, i + 1);
            const __hip_bfloat16* r0 = hb + s0 * H;
            const __hip_bfloat16* r1 = hb + s1 * H;
            float x00 = __bfloat162float(r0[lane]);
            float x01 = __bfloat162float(r0[lane + 64]);
            float x10 = __bfloat162float(r1[lane]);
            float x11 = __bfloat162float(r1[lane + 64]);
            float x02 = 0.f, x12 = 0.f;
            if (lane < H - 128) {
                x02 = __bfloat162float(r0[lane + 128]);
                x12 = __bfloat162float(r1[lane + 128]);
            }
            a0 += w0 * x00; a1 += w0 * x01; a2 += w0 * x02;
            b0 += w1 * x10; b1 += w1 * x11; b2 += w1 * x12;
        }
        if (i < deg) {
            int s0 = __shfl(sv, i);
            float w0 = __shfl(wv, i);
            const __hip_bfloat16* r0 = hb + s0 * H;
            a0 += w0 * __bfloat162float(r0[lane]);
            a1 += w0 * __bfloat162float(r0[lane + 64]);
            if (lane < H - 128) a2 += w0 * __bfloat162float(r0[lane + 128]);
        }
        a0 += b0 + c0 + e0; a1 += b1 + c1 + e1; a2 += b2 + c2 + e2;
    } else {
        // ---- fallback: serial two-pass (correct for any degree) ----
        float m = -1e30f;
        for (int i = beg; i < end; i++) {
            float e = hsb[srcs[i]] + hdv;
            e = (e > 0.f) ? e : 0.2f * e;
            m = fmaxf(m, e);
        }
        denom = 0.f;
        for (int i = beg; i < end; i++) {
            int s = srcs[i];
            float e = hsb[s] + hdv;
            e = (e > 0.f) ? e : 0.2f * e;
            float w = __expf(e - m);
            denom += w;
            const __hip_bfloat16* hr = hb + s * H;
            a0 += w * __bfloat162float(hr[lane]);
            a1 += w * __bfloat162float(hr[lane + 64]);
            if (lane < H - 128) a2 += w * __bfloat162float(hr[lane + 128]);
        }
    }

    float inv = 1.0f / denom;
    float o0 = a0 * inv + bias[lane];
    float o1 = a1 * inv + bias[lane + 64];
    float o2 = 0.f;
    if (lane < H - 128) o2 = a2 * inv + bias[lane + 128];

    // ---- store in MFMA-fragment-packed order (bit-identical data) ----
    int tile = node >> 4, rt = node & 15;
    __hip_bfloat16* fh = &g_hAfhi[tile * TSTRIDE];
    __hip_bfloat16* fl = &g_hAflo[tile * TSTRIDE];
    {
        int f = lane;
        int idx = (f >> 5) * 512 + (rt + ((f >> 3) & 3) * 16) * 8 + (f & 7);
        __hip_bfloat16 hi = __float2bfloat16(o0);
        fh[idx] = hi; fl[idx] = __float2bfloat16(o0 - __bfloat162float(hi));
    }
    {
        int f = lane + 64;
        int idx = (f >> 5) * 512 + (rt + ((f >> 3) & 3) * 16) * 8 + (f & 7);
        __hip_bfloat16 hi = __float2bfloat16(o1);
        fh[idx] = hi; fl[idx] = __float2bfloat16(o1 - __bfloat162float(hi));
    }
    if (lane < H - 128) {
        int f = lane + 128;
        int idx = (f >> 5) * 512 + (rt + ((f >> 3) & 3) * 16) * 8 + (f & 7);
        __hip_bfloat16 hi = __float2bfloat16(o2);
        fh[idx] = hi; fl[idx] = __float2bfloat16(o2 - __bfloat162float(hi));
    }
    if (lane == 0) {       // zero pad k=152..159 for this node's row
        bf16x8 z = (bf16x8){0, 0, 0, 0, 0, 0, 0, 0};
        *(bf16x8*)&fh[4 * 512 + (rt + 48) * 8] = z;
        *(bf16x8*)&fl[4 * 512 + (rt + 48) * 8] = z;
    }

    // ---- fused pooling: block-level LDS reduce, then global atomics ----
    __shared__ float sp[3][64];
    if (wave == 0) { sp[0][lane] = 0.f; sp[1][lane] = 0.f; sp[2][lane] = 0.f; }
    __syncthreads();
    atomicAdd(&sp[0][lane], o0);
    atomicAdd(&sp[1][lane], o1);
    if (lane < H - 128) atomicAdd(&sp[2][lane], o2);
    __syncthreads();
    if (wave == 0) {
        float* pb = g_pooled + b * FC_IN + pool_off;
        atomicAdd(&pb[lane], sp[0][lane]);
        atomicAdd(&pb[lane + 64], sp[1][lane]);
        if (lane < H - 128) atomicAdd(&pb[lane + 128], sp[2][lane]);
    }
}

// ---------------- MLP head ----------------
__global__ __launch_bounds__(256) void k_mlp(const float* __restrict__ fc1W, const float* __restrict__ fc1b,
                                             const float* __restrict__ fc2W, const float* __restrict__ fc2b,
                                             const float* __restrict__ fc3W, const float* __restrict__ fc3b,
                                             float* __restrict__ out) {
    int b = blockIdx.x, t = threadIdx.x;
    __shared__ float p[FC_IN];
    __shared__ float h1[256];
    __shared__ float h2[128];
    const float invN = 1.0f / N;
    for (int i = t; i < FC_IN; i += 256) p[i] = g_pooled[b * FC_IN + i] * invN;
    __syncthreads();
    float acc = fc1b[t];
    for (int k = 0; k < FC_IN; k++) acc += p[k] * fc1W[k * 256 + t];
    h1[t] = acc;
    __syncthreads();
    if (t < 128) {
        float a = fc2b[t];
        for (int k = 0; k < 256; k++) a += h1[k] * fc2W[k * 128 + t];
        h2[t] = a;
    }
    __syncthreads();
    if (t < NC) {
        float a = fc3b[t];
        for (int k = 0; k < 128; k++) a += h2[k] * fc3W[k * NC + t];
        out[b * NC + t] = a;
    }
}

// ---------------- launch ----------------
extern "C" void kernel_launch(void* const* d_in, const int* in_sizes, int n_in,
                              void* d_out, int out_size, void* d_ws, size_t ws_size,
                              hipStream_t stream) {
    const float* x    = (const float*)d_in[0];
    const int*   ei   = (const int*)d_in[1];
    const float* W1   = (const float*)d_in[2];
    const float* as1  = (const float*)d_in[3];
    const float* ad1  = (const float*)d_in[4];
    const float* b1   = (const float*)d_in[5];
    const float* W234 = (const float*)d_in[6];
    const float* as234= (const float*)d_in[7];
    const float* ad234= (const float*)d_in[8];
    const float* b234 = (const float*)d_in[9];
    const float* fc1W = (const float*)d_in[10];
    const float* fc1b = (const float*)d_in[11];
    const float* fc2W = (const float*)d_in[12];
    const float* fc2b = (const float*)d_in[13];
    const float* fc3W = (const float*)d_in[14];
    const float* fc3b = (const float*)d_in[15];
    float* out = (float*)d_out;

    hipLaunchKernelGGL(k_zero, dim3(256), dim3(256), 0, stream);
    hipLaunchKernelGGL(k_packW, dim3((3 * NFRAG * 8 + 255) / 256), dim3(256), 0, stream, W234);
    hipLaunchKernelGGL(k_count, dim3((B * E + 255) / 256), dim3(256), 0, stream, ei);
    hipLaunchKernelGGL(k_scan, dim3(B), dim3(1024), 0, stream);
    hipLaunchKernelGGL(k_scatter, dim3((B * E + 255) / 256), dim3(256), 0, stream, ei);
    hipLaunchKernelGGL(k_pool_x, dim3(B), dim3(256), 0, stream, x);

    // Layer 1: fused transform + hs/hd, then aggregate(+pool)
    hipLaunchKernelGGL(k_layer1, dim3(B * N / 4), dim3(256), 0, stream, x, W1, as1, ad1);
    hipLaunchKernelGGL(k_aggregate, dim3(B * N / 4), dim3(256), 0, stream, b1, 3);

    // Layers 2-4: split-precision MFMA GEMM (fused hs/hd) + aggregate(+pool)
    for (int l = 0; l < 3; l++) {
        hipLaunchKernelGGL(k_gemm_mfma, dim3(256), dim3(1024), 0, stream,
                           l, as234 + l * H, ad234 + l * H);
        hipLaunchKernelGGL(k_aggregate, dim3(B * N / 4), dim3(256), 0, stream,
                           b234 + l * H, 3 + H + l * H);
    }

    hipLaunchKernelGGL(k_mlp, dim3(B), dim3(256), 0, stream,
                       fc1W, fc1b, fc2W, fc2b, fc3W, fc3b, out);
}